// Round 10
// baseline (155.114 us; speedup 1.0000x reference)
//
#include <hip/hip_runtime.h>
#include <cstdint>

typedef _Float16 f16;
typedef _Float16 f16x2 __attribute__((ext_vector_type(2)));
typedef _Float16 f16x8 __attribute__((ext_vector_type(8)));
typedef float    f32x4 __attribute__((ext_vector_type(4)));

static __device__ __forceinline__ uint32_t pack2(float x, float y) {
    f16 hx = (f16)x, hy = (f16)y;
    uint32_t ux = __builtin_bit_cast(unsigned short, hx);
    uint32_t uy = __builtin_bit_cast(unsigned short, hy);
    return ux | (uy << 16);
}

// ---------------------------------------------------------------------------
// Kernel 1 (fused transpose+gemm, one block per batch, PIPELINED v3):
// r8/r9 post-mortem: spill (WRITE 160-172MB) came from __launch_bounds__
// (512,2)'s 256-reg promise -- the kernel needs ~316 unified regs (124 V +
// 192 acc AGPR) even WITHOUT prefetch; r7 sat exactly at the cliff and any
// prefetch regs pushed it over.  Occupancy was 1 block/CU anyway, so the
// (512,2) declaration bought nothing.  Fix: __launch_bounds__(512,1) ->
// 512-reg budget, prefetch fits, no spill, same runtime occupancy.
// Keep: dual-plane reg prefetch BEFORE the barrier + raw lgkmcnt-only
// barrier (prefetch stays in flight across it).  Double-buffered LDS,
// one barrier per K-step.  Staging map/swizzle/MFMA order = r7 (verified).
// ---------------------------------------------------------------------------
__global__ __launch_bounds__(512, 1) void k_gemm(const float* __restrict__ Are,
                                                 const float* __restrict__ Aim,
                                                 f16* __restrict__ AhAre,
                                                 f16* __restrict__ AhAim) {
    const int tid = threadIdx.x;
    const int b = blockIdx.x;

    __shared__ __align__(16) f16 ls[2][2][256 * 32];   // [buf][Re,Im]: 256r x 32k

    const int l = tid & 63, g = tid >> 6;      // lane, wave 0..7
    const int lr = l & 15, lk = l >> 4;

    // staging decomposition: u = m-pair 0..15, fp = row-group of 8 (0..31)
    const int u = tid & 15;
    const int fp = tid >> 4;
    const int su = u >> 2, uq = u & 3;

    f32x4 cR[16], cI[16], dR[8], dI[8];
#pragma unroll
    for (int j = 0; j < 16; ++j) { cR[j] = (f32x4)0.0f; cI[j] = (f32x4)0.0f; }
#pragma unroll
    for (int j = 0; j < 8; ++j)  { dR[j] = (f32x4)0.0f; dI[j] = (f32x4)0.0f; }

    // ---- prologue: load tile 0 into regs (both planes)
    float4 v[2][4];
#pragma unroll
    for (int t = 0; t < 2; ++t) {
        const float* sp = (t ? Aim : Are) + (size_t)b * 65536
                        + (size_t)(2 * u) * 256 + fp * 8;
        v[t][0] = *(const float4*)(sp);
        v[t][1] = *(const float4*)(sp + 4);
        v[t][2] = *(const float4*)(sp + 256);
        v[t][3] = *(const float4*)(sp + 260);
    }

#pragma unroll
    for (int step = 0; step < 8; ++step) {
        const int p = step & 1;

        // ---- pack current tile regs -> LDS[p] (swizzled slots, verified map)
#pragma unroll
        for (int t = 0; t < 2; ++t) {
            float xv[8] = {v[t][0].x, v[t][0].y, v[t][0].z, v[t][0].w,
                           v[t][1].x, v[t][1].y, v[t][1].z, v[t][1].w};
            float yv[8] = {v[t][2].x, v[t][2].y, v[t][2].z, v[t][2].w,
                           v[t][3].x, v[t][3].y, v[t][3].z, v[t][3].w};
            uint32_t* lw = (uint32_t*)&ls[p][t][0];
#pragma unroll
            for (int i = 0; i < 8; ++i) {
                int r = fp * 8 + i;
                int s = su ^ ((r >> 1) & 3);
                lw[r * 16 + s * 4 + uq] = pack2(xv[i], yv[i]);
            }
        }

        // ---- prefetch tile step+1 (both planes) BEFORE the barrier:
        // lands during this step's MFMA phase.  (512,1) budget -> no spill.
        if (step < 7) {
            const int m0n = 32 * (step + 1);
#pragma unroll
            for (int t = 0; t < 2; ++t) {
                const float* sp = (t ? Aim : Are) + (size_t)b * 65536
                                + (size_t)(m0n + 2 * u) * 256 + fp * 8;
                v[t][0] = *(const float4*)(sp);
                v[t][1] = *(const float4*)(sp + 4);
                v[t][2] = *(const float4*)(sp + 256);
                v[t][3] = *(const float4*)(sp + 260);
            }
        }

        // raw barrier: drain LDS writes only -- prefetch stays in flight
        asm volatile("s_waitcnt lgkmcnt(0)\n\ts_barrier" ::: "memory");

        // ---- compute from LDS[p]
        const f16* lsR = &ls[p][0][0];
        const f16* lsI = &ls[p][1][0];

        const int r1 = 16 * g + lr;
        const int r2 = 128 + 16 * g + lr;
        const int s1 = lk ^ ((r1 >> 1) & 3);
        const int s2 = lk ^ ((r2 >> 1) & 3);
        f16x8 a1re = *(const f16x8*)(&lsR[r1 * 32 + s1 * 8]);
        uint4 u1   = *(const uint4*)(&lsI[r1 * 32 + s1 * 8]);
        f16x8 a2re = *(const f16x8*)(&lsR[r2 * 32 + s2 * 8]);
        uint4 u2   = *(const uint4*)(&lsI[r2 * 32 + s2 * 8]);
        f16x8 a1im = __builtin_bit_cast(f16x8, u1);
        f16x8 a2im = __builtin_bit_cast(f16x8, u2);
        uint4 n1 = make_uint4(u1.x ^ 0x80008000u, u1.y ^ 0x80008000u,
                              u1.z ^ 0x80008000u, u1.w ^ 0x80008000u);
        uint4 n2 = make_uint4(u2.x ^ 0x80008000u, u2.y ^ 0x80008000u,
                              u2.z ^ 0x80008000u, u2.w ^ 0x80008000u);
        f16x8 na1 = __builtin_bit_cast(f16x8, n1);
        f16x8 na2 = __builtin_bit_cast(f16x8, n2);

#pragma unroll
        for (int j = 0; j < 16; ++j) {
            int rb = 16 * j + lr;
            int sb = lk ^ ((rb >> 1) & 3);
            f16x8 bre = *(const f16x8*)(&lsR[rb * 32 + sb * 8]);
            f16x8 bim = *(const f16x8*)(&lsI[rb * 32 + sb * 8]);
            cR[j] = __builtin_amdgcn_mfma_f32_16x16x32_f16(a1re, bre, cR[j], 0, 0, 0);
            cR[j] = __builtin_amdgcn_mfma_f32_16x16x32_f16(a1im, bim, cR[j], 0, 0, 0);
            cI[j] = __builtin_amdgcn_mfma_f32_16x16x32_f16(a1re, bim, cI[j], 0, 0, 0);
            cI[j] = __builtin_amdgcn_mfma_f32_16x16x32_f16(na1,  bre, cI[j], 0, 0, 0);
            if (j >= 8) {
                dR[j-8] = __builtin_amdgcn_mfma_f32_16x16x32_f16(a2re, bre, dR[j-8], 0, 0, 0);
                dR[j-8] = __builtin_amdgcn_mfma_f32_16x16x32_f16(a2im, bim, dR[j-8], 0, 0, 0);
                dI[j-8] = __builtin_amdgcn_mfma_f32_16x16x32_f16(a2re, bim, dI[j-8], 0, 0, 0);
                dI[j-8] = __builtin_amdgcn_mfma_f32_16x16x32_f16(na2,  bre, dI[j-8], 0, 0, 0);
            }
        }
    }

    f16* oR = AhAre + (size_t)b * 65536;
    f16* oI = AhAim + (size_t)b * 65536;

    // direct epilogue: rows 16g (all cols), rows 128+16g (cols 128..255)
#pragma unroll
    for (int j = 0; j < 16; ++j)
#pragma unroll
        for (int r = 0; r < 4; ++r) {
            int n = 16 * g + lk * 4 + r;
            int c = 16 * j + lr;
            oR[(size_t)n * 256 + c] = (f16)cR[j][r];
            oI[(size_t)n * 256 + c] = (f16)cI[j][r];
        }
#pragma unroll
    for (int j = 0; j < 8; ++j)
#pragma unroll
        for (int r = 0; r < 4; ++r) {
            int n = 128 + 16 * g + lk * 4 + r;
            int c = 128 + 16 * j + lr;
            oR[(size_t)n * 256 + c] = (f16)dR[j][r];
            oI[(size_t)n * 256 + c] = (f16)dI[j][r];
        }

    // Hermitian mirror: q3[128+jj][nn] = conj(q1[nn][128+jj]); q1 = cR/cI[j>=8]
    f16* lsm = &ls[0][0][0];                    // reuse 32KB as [128][128]
    const int jj_out = tid >> 2, qtr = tid & 3; // 128 rows x 4 thread-quarters

    __syncthreads();                            // all waves past last ls reads
    // Re plane: copy
#pragma unroll
    for (int j = 8; j < 16; ++j)
#pragma unroll
        for (int r = 0; r < 4; ++r) {
            int jj = 16 * (j - 8) + lr;
            int nn = 16 * g + lk * 4 + r;
            lsm[jj * 128 + nn] = (f16)cR[j][r];
        }
    __syncthreads();
    {
        const f16* srow = lsm + jj_out * 128 + qtr * 32;
        f16* drow = oR + (size_t)(128 + jj_out) * 256 + qtr * 32;
#pragma unroll
        for (int ch = 0; ch < 4; ++ch)
            *(uint4*)(void*)(drow + ch * 8) = *(const uint4*)(srow + ch * 8);
    }
    __syncthreads();
    // Im plane: negate
#pragma unroll
    for (int j = 8; j < 16; ++j)
#pragma unroll
        for (int r = 0; r < 4; ++r) {
            int jj = 16 * (j - 8) + lr;
            int nn = 16 * g + lk * 4 + r;
            lsm[jj * 128 + nn] = (f16)(-cI[j][r]);
        }
    __syncthreads();
    {
        const f16* srow = lsm + jj_out * 128 + qtr * 32;
        f16* drow = oI + (size_t)(128 + jj_out) * 256 + qtr * 32;
#pragma unroll
        for (int ch = 0; ch < 4; ++ch)
            *(uint4*)(void*)(drow + ch * 8) = *(const uint4*)(srow + ch * 8);
    }
}

// ---------------------------------------------------------------------------
// Kernel 2: power iteration, 8-WAVE / 32-ROWS-PER-WAVE form (unchanged:
// ~25-28us).  Deferred normalization (stable form).
// ---------------------------------------------------------------------------
static __device__ __forceinline__ void matvec2(const f16x8 (&afr)[2][16],
                                               const f16* __restrict__ vs, int h,
                                               float4 (&y)[2]) {
    f16x8 bf[16];
#pragma unroll
    for (int c = 0; c < 16; ++c) bf[c] = *(const f16x8*)(vs + 32 * c + 8 * h);
    f32x4 P0[2], P1[2];
#pragma unroll
    for (int rg = 0; rg < 2; ++rg) { P0[rg] = (f32x4)0.0f; P1[rg] = (f32x4)0.0f; }
#pragma unroll
    for (int c = 0; c < 16; ++c) {
#pragma unroll
        for (int rg = 0; rg < 2; ++rg) {
            if (c & 1) P1[rg] = __builtin_amdgcn_mfma_f32_16x16x32_f16(afr[rg][c], bf[c], P1[rg], 0, 0, 0);
            else       P0[rg] = __builtin_amdgcn_mfma_f32_16x16x32_f16(afr[rg][c], bf[c], P0[rg], 0, 0, 0);
        }
    }
#pragma unroll
    for (int rg = 0; rg < 2; ++rg)
        y[rg] = make_float4(P0[rg][0] + P1[rg][0], P0[rg][1] + P1[rg][1],
                            P0[rg][2] + P1[rg][2], P0[rg][3] + P1[rg][3]);
}

__global__ __launch_bounds__(512, 2) void k_power(const f16* __restrict__ AhAre,
                                                  const f16* __restrict__ AhAim,
                                                  const float* __restrict__ vre,
                                                  const float* __restrict__ vim,
                                                  const int* __restrict__ pniter,
                                                  float* __restrict__ out) {
    const int tid = threadIdx.x;
    const int b = blockIdx.x;
    const int l = tid & 63;            // lane
    const int g = tid >> 6;            // wave 0..7
    const int sel = l & 15;            // A-row-within-group / B-col
    const int h = l >> 4;              // k-slot 0..3

    __shared__ __align__(16) f16 v0h[2][512];   // [buf][ vr ; -vi ]
    __shared__ __align__(16) f16 v1h[2][512];   // [buf][ vi ;  vr ]
    __shared__ __align__(16) float part[2][8];

    // ---- load A fragments: wave g owns rows 32g .. 32g+31 (2 row-groups)
    f16x8 afr[2][16];
#pragma unroll
    for (int rg = 0; rg < 2; ++rg) {
        const int m = 32 * g + 16 * rg + sel;
        const f16* bR = AhAre + (size_t)b * 65536 + (size_t)m * 256 + 8 * h;
        const f16* bI = AhAim + (size_t)b * 65536 + (size_t)m * 256 + 8 * h;
#pragma unroll
        for (int c = 0; c < 8; ++c) {
            afr[rg][c]     = *(const f16x8*)(bR + 32 * c);
            afr[rg][8 + c] = *(const f16x8*)(bI + 32 * c);
        }
    }
#pragma unroll
    for (int rg = 0; rg < 2; ++rg)
#pragma unroll
        for (int c = 0; c < 16; ++c) asm volatile("" : "+a"(afr[rg][c]));

    if (tid < 256) {
        float xr = vre[b * 256 + tid], xi = vim[b * 256 + tid];
        v0h[0][tid]       = (f16)xr;
        v0h[0][256 + tid] = (f16)(-xi);
        v1h[0][tid]       = (f16)xi;
        v1h[0][256 + tid] = (f16)xr;
    }
    __syncthreads();

    const int niter = *pniter;
    const f16* vsel = (sel == 0) ? &v0h[0][0] : &v1h[0][0];

    float eig = 0.0f;

    auto npart = [&](int wb, const float4 (&y)[2]) {
        float s_ = 0.0f;
        if (sel < 2) {
#pragma unroll
            for (int rg = 0; rg < 2; ++rg)
                s_ += y[rg].x * y[rg].x + y[rg].y * y[rg].y
                    + y[rg].z * y[rg].z + y[rg].w * y[rg].w;
        }
        s_ += __shfl_xor(s_, 1, 64);
        s_ += __shfl_xor(s_, 16, 64);
        s_ += __shfl_xor(s_, 32, 64);
        if (l == 0) part[wb][g] = s_;
    };
    auto vwrite = [&](int wb, const float4 (&y)[2], float sc) {
        if (sel < 2) {
#pragma unroll
            for (int rg = 0; rg < 2; ++rg) {
                uint32_t w0 = pack2(y[rg].x * sc, y[rg].y * sc);
                uint32_t w1 = pack2(y[rg].z * sc, y[rg].w * sc);
                int m0 = 32 * g + 16 * rg + 4 * h;    // 4 consecutive rows
                if (sel == 0) {                       // y = new vr
                    *(uint2*)(void*)(&v0h[wb][m0])       = make_uint2(w0, w1);
                    *(uint2*)(void*)(&v1h[wb][256 + m0]) = make_uint2(w0, w1);
                } else {                              // y = new vi
                    *(uint2*)(void*)(&v1h[wb][m0])       = make_uint2(w0, w1);
                    *(uint2*)(void*)(&v0h[wb][256 + m0]) =
                        make_uint2(w0 ^ 0x80008000u, w1 ^ 0x80008000u);
                }
            }
        }
    };
    auto psum = [&](int rb) -> float {
        float4 q0 = *(const float4*)(&part[rb][0]);
        float4 q1 = *(const float4*)(&part[rb][4]);
        return (q0.x + q0.y + q0.z + q0.w) + (q1.x + q1.y + q1.z + q1.w);
    };

    float sc_m1 = 1.0f;   // s_{t-1}
    float nm2   = 1.0f;   // n_{t-2}

    float4 y[2];

    // ---- peeled iteration 1 (synchronous): u_1 = y_1/e_1, n_1 = 1 ----
    if (niter >= 1) {
        matvec2(afr, vsel, h, y);
        npart(1, y);
        __syncthreads();
        float e1v = sqrtf(psum(1));
        float sc  = __builtin_amdgcn_rcpf(e1v + 1e-6f);
        vwrite(1, y, sc);
        eig = e1v;
        __syncthreads();
    }
    // ---- peeled iteration 2 (synchronous): u_2 = y_2/e_2, n_2 = 1 ----
    if (niter >= 2) {
        matvec2(afr, vsel + 512, h, y);
        npart(0, y);
        __syncthreads();
        float e2v = sqrtf(psum(0));
        float sc  = __builtin_amdgcn_rcpf(e2v + 1e-6f);
        vwrite(0, y, sc);
        eig = e2v;
        sc_m1 = sc;   // s_2
        nm2   = 1.0f; // n_1
        __syncthreads();
    }

    // ---- pipelined iterations 3..niter: one barrier each ----
    int wr = 0;
    for (int t = 3; t <= niter; ++t) {
        const int rd = wr;    // buffer holding u_{t-1}, part[rd] = q_{t-1}
        wr ^= 1;
        float q   = psum(rd);                                  // ||y_{t-1}||^2
        float e1v = __builtin_amdgcn_sqrtf(q);                 // e_{t-1}
        float nm1 = e1v * sc_m1;                               // n_{t-1}
        float sc  = nm2 * __builtin_amdgcn_rcpf(e1v * nm1 + 1e-12f);  // s_t
        matvec2(afr, vsel + (size_t)rd * 512, h, y);           // y_t
        vwrite(wr, y, sc);
        npart(wr, y);
        nm2 = nm1; sc_m1 = sc;
        __syncthreads();
    }

    // ---- epilogue: exact eig = ||y_T|| / n_{T-1}
    if (niter >= 3) {
        float qT = psum(wr);
        eig = sqrtf(qT) / (nm2 + 1e-12f);
    }
    if (tid == 0) out[b] = eig;
}

extern "C" void kernel_launch(void* const* d_in, const int* in_sizes, int n_in,
                              void* d_out, int out_size, void* d_ws, size_t ws_size,
                              hipStream_t stream) {
    const float* Are = (const float*)d_in[0];
    const float* Aim = (const float*)d_in[1];
    const float* vre = (const float*)d_in[2];
    const float* vim = (const float*)d_in[3];
    const int* niter = (const int*)d_in[4];
    float* out = (float*)d_out;

    f16* AhAre = (f16*)d_ws;                                            // 32 MB
    f16* AhAim = (f16*)((char*)d_ws + (size_t)32 * 1024 * 1024);        // 32 MB

    k_gemm<<<dim3(256), dim3(512), 0, stream>>>(Are, Aim, AhAre, AhAim);
    k_power<<<dim3(256), dim3(512), 0, stream>>>(AhAre, AhAim, vre, vim, niter, out);
}

// Round 11
// 98.886 us; speedup vs baseline: 1.5686x; 1.5686x over previous
//
#include <hip/hip_runtime.h>
#include <cstdint>

typedef _Float16 f16;
typedef _Float16 f16x2 __attribute__((ext_vector_type(2)));
typedef _Float16 f16x8 __attribute__((ext_vector_type(8)));
typedef float    f32x4 __attribute__((ext_vector_type(4)));

static __device__ __forceinline__ uint32_t pack2(float x, float y) {
    f16 hx = (f16)x, hy = (f16)y;
    uint32_t ux = __builtin_bit_cast(unsigned short, hx);
    uint32_t uy = __builtin_bit_cast(unsigned short, hy);
    return ux | (uy << 16);
}

// ---------------------------------------------------------------------------
// Kernel 1 (fused transpose+gemm, one block per batch, TWO-PASS PIPELINED):
// r8-r10 post-mortem: any 512-thread block is HARD-CAPPED at 256 unified
// regs/thread (2 waves/SIMD x 512-reg file); r7's single-pass form sat at
// ~252/256, so prefetch regs always spilled (WRITE_SIZE 160-230MB).
// Fix: split into two sequential passes so peak acc footprint halves:
//   pass 0: rows 0..127  x cols 0..255  -> 128 acc regs/thread
//           (+ epilogue: direct store + Hermitian mirror -> frees accs)
//   pass 1: rows 128..255 x cols 128..255 -> 64 acc regs/thread,
//           stages only the lower 128 A-rows (half traffic).
// Peak ~200 regs -> prefetch fits.  A staged 1.5x (extra pass absorbed by
// L3: A=128MB < 256MB).  Pipeline: double-buffered LDS, reg-prefetch of
// tile t+1 issued BEFORE a raw lgkmcnt-only barrier (loads stay in flight
// across it).  Staging map/swizzle/MFMA K-order = r7 (verified, absmax 8).
// ---------------------------------------------------------------------------
__global__ __launch_bounds__(512, 2) void k_gemm(const float* __restrict__ Are,
                                                 const float* __restrict__ Aim,
                                                 f16* __restrict__ AhAre,
                                                 f16* __restrict__ AhAim) {
    const int tid = threadIdx.x;
    const int b = blockIdx.x;

    __shared__ __align__(16) f16 ls[2][2][256 * 32];   // [buf][Re,Im]

    const int l = tid & 63, g = tid >> 6;      // lane, wave 0..7
    const int lr = l & 15, lk = l >> 4;

    // staging decomposition: u = m-pair 0..15, fp = row-group (0..31)
    const int u = tid & 15;
    const int fp = tid >> 4;
    const int su = u >> 2, uq = u & 3;

    f16* oR = AhAre + (size_t)b * 65536;
    f16* oI = AhAim + (size_t)b * 65536;

    // ======================= PASS 0: rows 0..127, full width ================
    {
        f32x4 cR[16], cI[16];
#pragma unroll
        for (int j = 0; j < 16; ++j) { cR[j] = (f32x4)0.0f; cI[j] = (f32x4)0.0f; }

        // prologue: load tile 0 (full 256-row stage: 8 rows/thread/plane)
        float4 v[2][4];
#pragma unroll
        for (int t = 0; t < 2; ++t) {
            const float* sp = (t ? Aim : Are) + (size_t)b * 65536
                            + (size_t)(2 * u) * 256 + fp * 8;
            v[t][0] = *(const float4*)(sp);
            v[t][1] = *(const float4*)(sp + 4);
            v[t][2] = *(const float4*)(sp + 256);
            v[t][3] = *(const float4*)(sp + 260);
        }

#pragma unroll
        for (int step = 0; step < 8; ++step) {
            const int p = step & 1;

            // pack current tile -> LDS[p] (swizzled slots, verified map)
#pragma unroll
            for (int t = 0; t < 2; ++t) {
                float xv[8] = {v[t][0].x, v[t][0].y, v[t][0].z, v[t][0].w,
                               v[t][1].x, v[t][1].y, v[t][1].z, v[t][1].w};
                float yv[8] = {v[t][2].x, v[t][2].y, v[t][2].z, v[t][2].w,
                               v[t][3].x, v[t][3].y, v[t][3].z, v[t][3].w};
                uint32_t* lw = (uint32_t*)&ls[p][t][0];
#pragma unroll
                for (int i = 0; i < 8; ++i) {
                    int r = fp * 8 + i;
                    int s = su ^ ((r >> 1) & 3);
                    lw[r * 16 + s * 4 + uq] = pack2(xv[i], yv[i]);
                }
            }

            // prefetch tile step+1 BEFORE barrier (stays in flight across it)
            if (step < 7) {
                const int m0n = 32 * (step + 1);
#pragma unroll
                for (int t = 0; t < 2; ++t) {
                    const float* sp = (t ? Aim : Are) + (size_t)b * 65536
                                    + (size_t)(m0n + 2 * u) * 256 + fp * 8;
                    v[t][0] = *(const float4*)(sp);
                    v[t][1] = *(const float4*)(sp + 4);
                    v[t][2] = *(const float4*)(sp + 256);
                    v[t][3] = *(const float4*)(sp + 260);
                }
            }

            // raw barrier: drain LDS writes only
            asm volatile("s_waitcnt lgkmcnt(0)\n\ts_barrier" ::: "memory");

            const f16* lsR = &ls[p][0][0];
            const f16* lsI = &ls[p][1][0];

            const int r1 = 16 * g + lr;                 // 0..127
            const int s1 = lk ^ ((r1 >> 1) & 3);
            f16x8 a1re = *(const f16x8*)(&lsR[r1 * 32 + s1 * 8]);
            uint4 u1   = *(const uint4*)(&lsI[r1 * 32 + s1 * 8]);
            f16x8 a1im = __builtin_bit_cast(f16x8, u1);
            uint4 n1 = make_uint4(u1.x ^ 0x80008000u, u1.y ^ 0x80008000u,
                                  u1.z ^ 0x80008000u, u1.w ^ 0x80008000u);
            f16x8 na1 = __builtin_bit_cast(f16x8, n1);

#pragma unroll
            for (int j = 0; j < 16; ++j) {
                int rb = 16 * j + lr;
                int sb = lk ^ ((rb >> 1) & 3);
                f16x8 bre = *(const f16x8*)(&lsR[rb * 32 + sb * 8]);
                f16x8 bim = *(const f16x8*)(&lsI[rb * 32 + sb * 8]);
                cR[j] = __builtin_amdgcn_mfma_f32_16x16x32_f16(a1re, bre, cR[j], 0, 0, 0);
                cR[j] = __builtin_amdgcn_mfma_f32_16x16x32_f16(a1im, bim, cR[j], 0, 0, 0);
                cI[j] = __builtin_amdgcn_mfma_f32_16x16x32_f16(a1re, bim, cI[j], 0, 0, 0);
                cI[j] = __builtin_amdgcn_mfma_f32_16x16x32_f16(na1,  bre, cI[j], 0, 0, 0);
            }
        }

        // ---- pass-0 epilogue: direct store rows 16g (all cols)
#pragma unroll
        for (int j = 0; j < 16; ++j)
#pragma unroll
            for (int r = 0; r < 4; ++r) {
                int n = 16 * g + lk * 4 + r;
                int c = 16 * j + lr;
                oR[(size_t)n * 256 + c] = (f16)cR[j][r];
                oI[(size_t)n * 256 + c] = (f16)cI[j][r];
            }

        // ---- Hermitian mirror: q2[128+jj][nn] = conj(q1[nn][128+jj])
        f16* lsm = &ls[0][0][0];                    // reuse 32KB as [128][128]
        const int jj_out = tid >> 2, qtr = tid & 3;

        __syncthreads();                            // all ls reads done
        // Re plane: copy
#pragma unroll
        for (int j = 8; j < 16; ++j)
#pragma unroll
            for (int r = 0; r < 4; ++r) {
                int jj = 16 * (j - 8) + lr;
                int nn = 16 * g + lk * 4 + r;
                lsm[jj * 128 + nn] = (f16)cR[j][r];
            }
        __syncthreads();
        {
            const f16* srow = lsm + jj_out * 128 + qtr * 32;
            f16* drow = oR + (size_t)(128 + jj_out) * 256 + qtr * 32;
#pragma unroll
            for (int ch = 0; ch < 4; ++ch)
                *(uint4*)(void*)(drow + ch * 8) = *(const uint4*)(srow + ch * 8);
        }
        __syncthreads();
        // Im plane: negate
#pragma unroll
        for (int j = 8; j < 16; ++j)
#pragma unroll
            for (int r = 0; r < 4; ++r) {
                int jj = 16 * (j - 8) + lr;
                int nn = 16 * g + lk * 4 + r;
                lsm[jj * 128 + nn] = (f16)(-cI[j][r]);
            }
        __syncthreads();
        {
            const f16* srow = lsm + jj_out * 128 + qtr * 32;
            f16* drow = oI + (size_t)(128 + jj_out) * 256 + qtr * 32;
#pragma unroll
            for (int ch = 0; ch < 4; ++ch)
                *(uint4*)(void*)(drow + ch * 8) = *(const uint4*)(srow + ch * 8);
        }
        __syncthreads();                            // protect ls for pass 1
    }

    // =============== PASS 1: rows 128..255, cols 128..255 ===================
    {
        f32x4 dR[8], dI[8];
#pragma unroll
        for (int j = 0; j < 8; ++j) { dR[j] = (f32x4)0.0f; dI[j] = (f32x4)0.0f; }

        // half-stage map: rows n = 128 + fp*4 + i (4 rows/thread), m-pair 2u
        float4 w[2][2];
#pragma unroll
        for (int t = 0; t < 2; ++t) {
            const float* sp = (t ? Aim : Are) + (size_t)b * 65536
                            + (size_t)(2 * u) * 256 + 128 + fp * 4;
            w[t][0] = *(const float4*)(sp);
            w[t][1] = *(const float4*)(sp + 256);
        }

#pragma unroll
        for (int step = 0; step < 8; ++step) {
            const int p = step & 1;

            // pack half tile (local row rr = global - 128; swizzle formula
            // identical since 128 vanishes mod 4 in (r>>1)&3)
#pragma unroll
            for (int t = 0; t < 2; ++t) {
                float xv[4] = {w[t][0].x, w[t][0].y, w[t][0].z, w[t][0].w};
                float yv[4] = {w[t][1].x, w[t][1].y, w[t][1].z, w[t][1].w};
                uint32_t* lw = (uint32_t*)&ls[p][t][0];
#pragma unroll
                for (int i = 0; i < 4; ++i) {
                    int rr = fp * 4 + i;
                    int s = su ^ ((rr >> 1) & 3);
                    lw[rr * 16 + s * 4 + uq] = pack2(xv[i], yv[i]);
                }
            }

            if (step < 7) {
                const int m0n = 32 * (step + 1);
#pragma unroll
                for (int t = 0; t < 2; ++t) {
                    const float* sp = (t ? Aim : Are) + (size_t)b * 65536
                                    + (size_t)(m0n + 2 * u) * 256 + 128 + fp * 4;
                    w[t][0] = *(const float4*)(sp);
                    w[t][1] = *(const float4*)(sp + 256);
                }
            }

            asm volatile("s_waitcnt lgkmcnt(0)\n\ts_barrier" ::: "memory");

            const f16* lsR = &ls[p][0][0];
            const f16* lsI = &ls[p][1][0];

            const int r2 = 16 * g + lr;                 // local (global-128)
            const int s2 = lk ^ ((r2 >> 1) & 3);
            f16x8 a2re = *(const f16x8*)(&lsR[r2 * 32 + s2 * 8]);
            uint4 u2   = *(const uint4*)(&lsI[r2 * 32 + s2 * 8]);
            f16x8 a2im = __builtin_bit_cast(f16x8, u2);
            uint4 n2 = make_uint4(u2.x ^ 0x80008000u, u2.y ^ 0x80008000u,
                                  u2.z ^ 0x80008000u, u2.w ^ 0x80008000u);
            f16x8 na2 = __builtin_bit_cast(f16x8, n2);

#pragma unroll
            for (int j = 0; j < 8; ++j) {
                int rb = 16 * j + lr;                   // local
                int sb = lk ^ ((rb >> 1) & 3);
                f16x8 bre = *(const f16x8*)(&lsR[rb * 32 + sb * 8]);
                f16x8 bim = *(const f16x8*)(&lsI[rb * 32 + sb * 8]);
                dR[j] = __builtin_amdgcn_mfma_f32_16x16x32_f16(a2re, bre, dR[j], 0, 0, 0);
                dR[j] = __builtin_amdgcn_mfma_f32_16x16x32_f16(a2im, bim, dR[j], 0, 0, 0);
                dI[j] = __builtin_amdgcn_mfma_f32_16x16x32_f16(a2re, bim, dI[j], 0, 0, 0);
                dI[j] = __builtin_amdgcn_mfma_f32_16x16x32_f16(na2,  bre, dI[j], 0, 0, 0);
            }
        }

        // pass-1 epilogue: rows 128+16g, cols 128..255
#pragma unroll
        for (int j = 0; j < 8; ++j)
#pragma unroll
            for (int r = 0; r < 4; ++r) {
                int n = 128 + 16 * g + lk * 4 + r;
                int c = 128 + 16 * j + lr;
                oR[(size_t)n * 256 + c] = (f16)dR[j][r];
                oI[(size_t)n * 256 + c] = (f16)dI[j][r];
            }
    }
}

// ---------------------------------------------------------------------------
// Kernel 2: power iteration, 8-WAVE / 32-ROWS-PER-WAVE form (unchanged:
// ~25-28us).  Deferred normalization (stable form).
// ---------------------------------------------------------------------------
static __device__ __forceinline__ void matvec2(const f16x8 (&afr)[2][16],
                                               const f16* __restrict__ vs, int h,
                                               float4 (&y)[2]) {
    f16x8 bf[16];
#pragma unroll
    for (int c = 0; c < 16; ++c) bf[c] = *(const f16x8*)(vs + 32 * c + 8 * h);
    f32x4 P0[2], P1[2];
#pragma unroll
    for (int rg = 0; rg < 2; ++rg) { P0[rg] = (f32x4)0.0f; P1[rg] = (f32x4)0.0f; }
#pragma unroll
    for (int c = 0; c < 16; ++c) {
#pragma unroll
        for (int rg = 0; rg < 2; ++rg) {
            if (c & 1) P1[rg] = __builtin_amdgcn_mfma_f32_16x16x32_f16(afr[rg][c], bf[c], P1[rg], 0, 0, 0);
            else       P0[rg] = __builtin_amdgcn_mfma_f32_16x16x32_f16(afr[rg][c], bf[c], P0[rg], 0, 0, 0);
        }
    }
#pragma unroll
    for (int rg = 0; rg < 2; ++rg)
        y[rg] = make_float4(P0[rg][0] + P1[rg][0], P0[rg][1] + P1[rg][1],
                            P0[rg][2] + P1[rg][2], P0[rg][3] + P1[rg][3]);
}

__global__ __launch_bounds__(512, 2) void k_power(const f16* __restrict__ AhAre,
                                                  const f16* __restrict__ AhAim,
                                                  const float* __restrict__ vre,
                                                  const float* __restrict__ vim,
                                                  const int* __restrict__ pniter,
                                                  float* __restrict__ out) {
    const int tid = threadIdx.x;
    const int b = blockIdx.x;
    const int l = tid & 63;            // lane
    const int g = tid >> 6;            // wave 0..7
    const int sel = l & 15;            // A-row-within-group / B-col
    const int h = l >> 4;              // k-slot 0..3

    __shared__ __align__(16) f16 v0h[2][512];   // [buf][ vr ; -vi ]
    __shared__ __align__(16) f16 v1h[2][512];   // [buf][ vi ;  vr ]
    __shared__ __align__(16) float part[2][8];

    // ---- load A fragments: wave g owns rows 32g .. 32g+31 (2 row-groups)
    f16x8 afr[2][16];
#pragma unroll
    for (int rg = 0; rg < 2; ++rg) {
        const int m = 32 * g + 16 * rg + sel;
        const f16* bR = AhAre + (size_t)b * 65536 + (size_t)m * 256 + 8 * h;
        const f16* bI = AhAim + (size_t)b * 65536 + (size_t)m * 256 + 8 * h;
#pragma unroll
        for (int c = 0; c < 8; ++c) {
            afr[rg][c]     = *(const f16x8*)(bR + 32 * c);
            afr[rg][8 + c] = *(const f16x8*)(bI + 32 * c);
        }
    }
#pragma unroll
    for (int rg = 0; rg < 2; ++rg)
#pragma unroll
        for (int c = 0; c < 16; ++c) asm volatile("" : "+a"(afr[rg][c]));

    if (tid < 256) {
        float xr = vre[b * 256 + tid], xi = vim[b * 256 + tid];
        v0h[0][tid]       = (f16)xr;
        v0h[0][256 + tid] = (f16)(-xi);
        v1h[0][tid]       = (f16)xi;
        v1h[0][256 + tid] = (f16)xr;
    }
    __syncthreads();

    const int niter = *pniter;
    const f16* vsel = (sel == 0) ? &v0h[0][0] : &v1h[0][0];

    float eig = 0.0f;

    auto npart = [&](int wb, const float4 (&y)[2]) {
        float s_ = 0.0f;
        if (sel < 2) {
#pragma unroll
            for (int rg = 0; rg < 2; ++rg)
                s_ += y[rg].x * y[rg].x + y[rg].y * y[rg].y
                    + y[rg].z * y[rg].z + y[rg].w * y[rg].w;
        }
        s_ += __shfl_xor(s_, 1, 64);
        s_ += __shfl_xor(s_, 16, 64);
        s_ += __shfl_xor(s_, 32, 64);
        if (l == 0) part[wb][g] = s_;
    };
    auto vwrite = [&](int wb, const float4 (&y)[2], float sc) {
        if (sel < 2) {
#pragma unroll
            for (int rg = 0; rg < 2; ++rg) {
                uint32_t w0 = pack2(y[rg].x * sc, y[rg].y * sc);
                uint32_t w1 = pack2(y[rg].z * sc, y[rg].w * sc);
                int m0 = 32 * g + 16 * rg + 4 * h;    // 4 consecutive rows
                if (sel == 0) {                       // y = new vr
                    *(uint2*)(void*)(&v0h[wb][m0])       = make_uint2(w0, w1);
                    *(uint2*)(void*)(&v1h[wb][256 + m0]) = make_uint2(w0, w1);
                } else {                              // y = new vi
                    *(uint2*)(void*)(&v1h[wb][m0])       = make_uint2(w0, w1);
                    *(uint2*)(void*)(&v0h[wb][256 + m0]) =
                        make_uint2(w0 ^ 0x80008000u, w1 ^ 0x80008000u);
                }
            }
        }
    };
    auto psum = [&](int rb) -> float {
        float4 q0 = *(const float4*)(&part[rb][0]);
        float4 q1 = *(const float4*)(&part[rb][4]);
        return (q0.x + q0.y + q0.z + q0.w) + (q1.x + q1.y + q1.z + q1.w);
    };

    float sc_m1 = 1.0f;   // s_{t-1}
    float nm2   = 1.0f;   // n_{t-2}

    float4 y[2];

    // ---- peeled iteration 1 (synchronous): u_1 = y_1/e_1, n_1 = 1 ----
    if (niter >= 1) {
        matvec2(afr, vsel, h, y);
        npart(1, y);
        __syncthreads();
        float e1v = sqrtf(psum(1));
        float sc  = __builtin_amdgcn_rcpf(e1v + 1e-6f);
        vwrite(1, y, sc);
        eig = e1v;
        __syncthreads();
    }
    // ---- peeled iteration 2 (synchronous): u_2 = y_2/e_2, n_2 = 1 ----
    if (niter >= 2) {
        matvec2(afr, vsel + 512, h, y);
        npart(0, y);
        __syncthreads();
        float e2v = sqrtf(psum(0));
        float sc  = __builtin_amdgcn_rcpf(e2v + 1e-6f);
        vwrite(0, y, sc);
        eig = e2v;
        sc_m1 = sc;   // s_2
        nm2   = 1.0f; // n_1
        __syncthreads();
    }

    // ---- pipelined iterations 3..niter: one barrier each ----
    int wr = 0;
    for (int t = 3; t <= niter; ++t) {
        const int rd = wr;    // buffer holding u_{t-1}, part[rd] = q_{t-1}
        wr ^= 1;
        float q   = psum(rd);                                  // ||y_{t-1}||^2
        float e1v = __builtin_amdgcn_sqrtf(q);                 // e_{t-1}
        float nm1 = e1v * sc_m1;                               // n_{t-1}
        float sc  = nm2 * __builtin_amdgcn_rcpf(e1v * nm1 + 1e-12f);  // s_t
        matvec2(afr, vsel + (size_t)rd * 512, h, y);           // y_t
        vwrite(wr, y, sc);
        npart(wr, y);
        nm2 = nm1; sc_m1 = sc;
        __syncthreads();
    }

    // ---- epilogue: exact eig = ||y_T|| / n_{T-1}
    if (niter >= 3) {
        float qT = psum(wr);
        eig = sqrtf(qT) / (nm2 + 1e-12f);
    }
    if (tid == 0) out[b] = eig;
}

extern "C" void kernel_launch(void* const* d_in, const int* in_sizes, int n_in,
                              void* d_out, int out_size, void* d_ws, size_t ws_size,
                              hipStream_t stream) {
    const float* Are = (const float*)d_in[0];
    const float* Aim = (const float*)d_in[1];
    const float* vre = (const float*)d_in[2];
    const float* vim = (const float*)d_in[3];
    const int* niter = (const int*)d_in[4];
    float* out = (float*)d_out;

    f16* AhAre = (f16*)d_ws;                                            // 32 MB
    f16* AhAim = (f16*)((char*)d_ws + (size_t)32 * 1024 * 1024);        // 32 MB

    k_gemm<<<dim3(256), dim3(512), 0, stream>>>(Are, Aim, AhAre, AhAim);
    k_power<<<dim3(256), dim3(512), 0, stream>>>(AhAre, AhAim, vre, vim, niter, out);
}